// Round 1
// baseline (117.395 us; speedup 1.0000x reference)
//
#include <hip/hip_runtime.h>

#define RR 4
#define LRH 256
#define LRW 256
#define HRH 1024
#define HRW 1024
#define TW 32
#define TH 8
#define GW (TW + 2*RR)   // 40
#define GH (TH + 2*RR)   // 16

// Kernel 1: low-res 9x9 box stats (replication pad = clamp) -> A, b coefficients
__global__ __launch_bounds__(256) void lowres_coeffs(
    const float* __restrict__ lrx, const float* __restrict__ lry,
    float* __restrict__ Alr, float* __restrict__ Blr)
{
    int idx = blockIdx.x * 256 + threadIdx.x;
    if (idx >= 3 * LRH * LRW) return;
    int x = idx % LRW;
    int y = (idx / LRW) % LRH;
    int c = idx / (LRW * LRH);
    const float* px = lrx + c * LRH * LRW;
    const float* py = lry + c * LRH * LRW;
    float sx = 0.f, sy = 0.f, sxy = 0.f, sxx = 0.f;
    for (int dy = -RR; dy <= RR; ++dy) {
        int yy = min(max(y + dy, 0), LRH - 1);
        const float* rx = px + yy * LRW;
        const float* ry = py + yy * LRW;
        #pragma unroll
        for (int dx = -RR; dx <= RR; ++dx) {
            int xx = min(max(x + dx, 0), LRW - 1);
            float xv = rx[xx], yv = ry[xx];
            sx += xv; sy += yv; sxy += xv * yv; sxx += xv * xv;
        }
    }
    const float inv81 = 1.0f / 81.0f;
    float mx = sx * inv81, my = sy * inv81;
    float cov = sxy * inv81 - mx * my;
    float var = sxx * inv81 - mx * mx;
    float A = cov / (var + 2.0f);
    float B = my - A * mx;
    Alr[idx] = A;
    Blr[idx] = B;
}

// Kernel 2: fused bilinear upsample (align_corners=True) + 8-dir side-window
// stencil + argmin|d| + trunc/clamp.
__global__ __launch_bounds__(256) void stencil_kernel(
    const float* __restrict__ Alr, const float* __restrict__ Blr,
    const float* __restrict__ hrx, float* __restrict__ out)
{
    __shared__ float sA[GH][GW];
    __shared__ float sB[GH][GW];

    const int c  = blockIdx.z;
    const int X0 = blockIdx.x * TW;
    const int Y0 = blockIdx.y * TH;
    const int tid = threadIdx.y * TW + threadIdx.x;
    const float* Ac = Alr + c * LRH * LRW;
    const float* Bc = Blr + c * LRH * LRW;
    const float scale = 255.0f / 1023.0f;  // (src-1)/(out-1), f32 like ref

    // Stage upsampled A,b tile (+4 halo each side, hr coords clamped = rep-pad)
    for (int i = tid; i < GH * GW; i += 256) {
        int r   = i / GW;
        int col = i - r * GW;
        int gy = min(max(Y0 - RR + r, 0), HRH - 1);
        int gx = min(max(X0 - RR + col, 0), HRW - 1);
        float ty = (float)gy * scale;
        int iy = (int)ty; if (iy > LRH - 2) iy = LRH - 2;
        float fy = ty - (float)iy;
        float tx = (float)gx * scale;
        int ix = (int)tx; if (ix > LRW - 2) ix = LRW - 2;
        float fx = tx - (float)ix;
        const float* a0 = Ac + iy * LRW + ix;
        const float* b0 = Bc + iy * LRW + ix;
        float a_c0 = a0[0] * (1.0f - fy) + a0[LRW]     * fy;
        float a_c1 = a0[1] * (1.0f - fy) + a0[LRW + 1] * fy;
        float b_c0 = b0[0] * (1.0f - fy) + b0[LRW]     * fy;
        float b_c1 = b0[1] * (1.0f - fy) + b0[LRW + 1] * fy;
        sA[r][col] = a_c0 * (1.0f - fx) + a_c1 * fx;
        sB[r][col] = b_c0 * (1.0f - fx) + b_c1 * fx;
    }
    __syncthreads();

    const int tx = threadIdx.x, ty = threadIdx.y;
    // Separable side-window sums:
    //   hL = sum dx in [-4,0], hR = sum dx in [0,4], hF = hL+hR-center
    //   T = sum dy in [-4,0], B = sum dy in [0,4] (center row in both), C = center row
    float TLa=0,TRa=0,TFa=0,BLa=0,BRa=0,BFa=0;
    float TLb=0,TRb=0,TFb=0,BLb=0,BRb=0,BFb=0;
    float CLa=0,CRa=0,CFa=0,CLb=0,CRb=0,CFb=0;
    #pragma unroll
    for (int dy = -RR; dy <= RR; ++dy) {
        int r = ty + RR + dy;
        float hLa=0, hRa=0, hLb=0, hRb=0;
        #pragma unroll
        for (int dx = -RR; dx <= 0; ++dx) {
            int cc = tx + RR + dx;
            hLa += sA[r][cc]; hLb += sB[r][cc];
        }
        #pragma unroll
        for (int dx = 0; dx <= RR; ++dx) {
            int cc = tx + RR + dx;
            hRa += sA[r][cc]; hRb += sB[r][cc];
        }
        float ctrA = sA[r][tx + RR], ctrB = sB[r][tx + RR];
        float hFa = hLa + hRa - ctrA;
        float hFb = hLb + hRb - ctrB;
        if (dy <= 0) { TLa+=hLa; TRa+=hRa; TFa+=hFa; TLb+=hLb; TRb+=hRb; TFb+=hFb; }
        if (dy >= 0) { BLa+=hLa; BRa+=hRa; BFa+=hFa; BLb+=hLb; BRb+=hRb; BFb+=hFb; }
        if (dy == 0) { CLa=hLa; CRa=hRa; CFa=hFa; CLb=hLb; CRb=hRb; CFb=hFb; }
    }

    const int Y = Y0 + ty, X = X0 + tx;
    float xv = hrx[(c * HRH + Y) * HRW + X];
    const float i45 = 1.0f / 45.0f, i25 = 1.0f / 25.0f;
    float cA[8], cB[8];
    cA[0]=(TLa+BLa-CLa)*i45; cB[0]=(TLb+BLb-CLb)*i45;  // L
    cA[1]=(TRa+BRa-CRa)*i45; cB[1]=(TRb+BRb-CRb)*i45;  // R
    cA[2]=TFa*i45;           cB[2]=TFb*i45;            // U
    cA[3]=BFa*i45;           cB[3]=BFb*i45;            // D
    cA[4]=TLa*i25;           cB[4]=TLb*i25;            // NW
    cA[5]=TRa*i25;           cB[5]=TRb*i25;            // NE
    cA[6]=BLa*i25;           cB[6]=BLb*i25;            // SW
    cA[7]=BRa*i25;           cB[7]=BRb*i25;            // SE

    float best = 1e30f, bd = 0.f;
    #pragma unroll
    for (int i = 0; i < 8; ++i) {
        float d = cA[i] * xv + cB[i] - xv;
        float ad = fabsf(d);
        if (ad < best) { best = ad; bd = d; }   // strict < => first-occurrence argmin
    }
    float res = truncf(bd + xv);
    res = fminf(fmaxf(res, 0.0f), 255.0f);
    out[(c * HRH + Y) * HRW + X] = res;
}

extern "C" void kernel_launch(void* const* d_in, const int* in_sizes, int n_in,
                              void* d_out, int out_size, void* d_ws, size_t ws_size,
                              hipStream_t stream) {
    const float* lrx = (const float*)d_in[0];
    const float* lry = (const float*)d_in[1];
    const float* hrx = (const float*)d_in[2];
    (void)d_in[3]; (void)in_sizes; (void)n_in; (void)out_size; (void)ws_size;

    float* Alr = (float*)d_ws;                 // 3*256*256 floats
    float* Blr = Alr + 3 * LRH * LRW;          // 3*256*256 floats
    float* outp = (float*)d_out;

    int n_lr = 3 * LRH * LRW;
    lowres_coeffs<<<(n_lr + 255) / 256, 256, 0, stream>>>(lrx, lry, Alr, Blr);

    dim3 grid(HRW / TW, HRH / TH, 3);
    dim3 block(TW, TH);
    stencil_kernel<<<grid, block, 0, stream>>>(Alr, Blr, hrx, outp);
}

// Round 2
// 94.699 us; speedup vs baseline: 1.2397x; 1.2397x over previous
//
#include <hip/hip_runtime.h>

#define RR 4
#define LRH 256
#define LRW 256
#define HRH 1024
#define HRW 1024
#define TW 32
#define TH 8
#define GW (TW + 2*RR)   // 40
#define GH (TH + 2*RR)   // 16

// Kernel 1: low-res 9x9 box stats (replication pad = clamp) -> interleaved (A,B)
// Separable: stage (x,y,xy,xx) float4 -> horizontal 9-tap -> vertical 9-tap.
__global__ __launch_bounds__(256) void lowres_coeffs(
    const float* __restrict__ lrx, const float* __restrict__ lry,
    float2* __restrict__ AB)
{
    __shared__ float4 sV[GH][GW];   // x, y, xy, xx (padded tile)
    __shared__ float4 sH[GH][TW];   // horizontal 9-tap sums

    const int c  = blockIdx.z;
    const int X0 = blockIdx.x * TW, Y0 = blockIdx.y * TH;
    const int tid = threadIdx.y * TW + threadIdx.x;
    const float* px = lrx + c * LRH * LRW;
    const float* py = lry + c * LRH * LRW;

    for (int i = tid; i < GH * GW; i += 256) {
        int r = i / GW, col = i - r * GW;
        int gy = min(max(Y0 - RR + r, 0), LRH - 1);
        int gx = min(max(X0 - RR + col, 0), LRW - 1);
        float xv = px[gy * LRW + gx];
        float yv = py[gy * LRW + gx];
        sV[r][col] = make_float4(xv, yv, xv * yv, xv * xv);
    }
    __syncthreads();

    for (int i = tid; i < GH * TW; i += 256) {
        int r = i / TW, col = i - r * TW;
        float4 s = sV[r][col];
        #pragma unroll
        for (int k = 1; k < 9; ++k) {
            float4 v = sV[r][col + k];
            s.x += v.x; s.y += v.y; s.z += v.z; s.w += v.w;
        }
        sH[r][col] = s;
    }
    __syncthreads();

    const int tx = threadIdx.x, ty = threadIdx.y;
    float4 s = sH[ty][tx];
    #pragma unroll
    for (int k = 1; k < 9; ++k) {
        float4 v = sH[ty + k][tx];
        s.x += v.x; s.y += v.y; s.z += v.z; s.w += v.w;
    }
    const float inv81 = 1.0f / 81.0f;
    float mx = s.x * inv81, my = s.y * inv81;
    float cov = s.z * inv81 - mx * my;
    float var = s.w * inv81 - mx * mx;
    float A = cov / (var + 2.0f);
    float B = my - A * mx;
    AB[(c * LRH + Y0 + ty) * LRW + X0 + tx] = make_float2(A, B);
}

// Kernel 2: fused bilinear upsample (align_corners=True) + 8-dir side-window
// stencil + argmin|d| + trunc/clamp. Horizontal (hL,hR) sums computed
// cooperatively; vertical pass = 9 b128 + 9 b64 LDS reads per pixel.
__global__ __launch_bounds__(256) void stencil_kernel(
    const float2* __restrict__ AB,
    const float* __restrict__ hrx, float* __restrict__ out)
{
    __shared__ float2 sAB[GH][GW];  // upsampled (A,B), padded tile
    __shared__ float4 sH[GH][TW];   // hLa, hLb, hRa, hRb per (row, inner col)

    const int c  = blockIdx.z;
    const int X0 = blockIdx.x * TW, Y0 = blockIdx.y * TH;
    const int tid = threadIdx.y * TW + threadIdx.x;
    const float2* ABc = AB + c * LRH * LRW;
    const float scale = 255.0f / 1023.0f;  // (src-1)/(out-1)

    // Stage upsampled A,B tile (+4 halo, hr coords clamped = rep-pad)
    for (int i = tid; i < GH * GW; i += 256) {
        int r = i / GW, col = i - r * GW;
        int gy = min(max(Y0 - RR + r, 0), HRH - 1);
        int gx = min(max(X0 - RR + col, 0), HRW - 1);
        float tyf = (float)gy * scale;
        int iy = (int)tyf; if (iy > LRH - 2) iy = LRH - 2;
        float fy = tyf - (float)iy;
        float txf = (float)gx * scale;
        int ix = (int)txf; if (ix > LRW - 2) ix = LRW - 2;
        float fx = txf - (float)ix;
        float2 v00 = ABc[iy * LRW + ix];
        float2 v01 = ABc[iy * LRW + ix + 1];
        float2 v10 = ABc[(iy + 1) * LRW + ix];
        float2 v11 = ABc[(iy + 1) * LRW + ix + 1];
        float a0 = v00.x * (1.0f - fy) + v10.x * fy;
        float a1 = v01.x * (1.0f - fy) + v11.x * fy;
        float b0 = v00.y * (1.0f - fy) + v10.y * fy;
        float b1 = v01.y * (1.0f - fy) + v11.y * fy;
        sAB[r][col] = make_float2(a0 * (1.0f - fx) + a1 * fx,
                                  b0 * (1.0f - fx) + b1 * fx);
    }
    __syncthreads();

    // Horizontal half-window sums: hL = cols [c-4..c], hR = cols [c..c+4]
    for (int i = tid; i < GH * TW; i += 256) {
        int r = i / TW, col = i - r * TW;
        float hLa = 0, hLb = 0, hRa = 0, hRb = 0;
        #pragma unroll
        for (int k = 0; k <= 4; ++k) {
            float2 v = sAB[r][col + k];
            hLa += v.x; hLb += v.y;
        }
        #pragma unroll
        for (int k = 4; k <= 8; ++k) {
            float2 v = sAB[r][col + k];
            hRa += v.x; hRb += v.y;
        }
        sH[r][col] = make_float4(hLa, hLb, hRa, hRb);
    }
    __syncthreads();

    const int tx = threadIdx.x, ty = threadIdx.y;
    // Vertical: T = rows [y-4..y], B = rows [y..y+4], C = center row.
    // Full-width col sum per row = hL + hR - center elem (read from sAB).
    float TLa=0,TLb=0,TRa=0,TRb=0, BLa=0,BLb=0,BRa=0,BRb=0;
    float Tca=0,Tcb=0, Bca=0,Bcb=0;
    float CLa=0,CLb=0,CRa=0,CRb=0, Cca=0,Ccb=0;
    #pragma unroll
    for (int k = 0; k < 9; ++k) {
        float4 h = sH[ty + k][tx];
        float2 cv = sAB[ty + k][tx + RR];
        if (k <= 4) { TLa+=h.x; TLb+=h.y; TRa+=h.z; TRb+=h.w; Tca+=cv.x; Tcb+=cv.y; }
        if (k >= 4) { BLa+=h.x; BLb+=h.y; BRa+=h.z; BRb+=h.w; Bca+=cv.x; Bcb+=cv.y; }
        if (k == 4) { CLa=h.x; CLb=h.y; CRa=h.z; CRb=h.w; Cca=cv.x; Ccb=cv.y; }
    }

    const int Y = Y0 + ty, X = X0 + tx;
    float xv = hrx[(c * HRH + Y) * HRW + X];
    const float i45 = 1.0f / 45.0f, i25 = 1.0f / 25.0f;
    float cA[8], cB[8];
    cA[0]=(TLa+BLa-CLa)*i45;      cB[0]=(TLb+BLb-CLb)*i45;       // L
    cA[1]=(TRa+BRa-CRa)*i45;      cB[1]=(TRb+BRb-CRb)*i45;       // R
    cA[2]=(TLa+TRa-Tca)*i45;      cB[2]=(TLb+TRb-Tcb)*i45;       // U
    cA[3]=(BLa+BRa-Bca)*i45;      cB[3]=(BLb+BRb-Bcb)*i45;       // D
    cA[4]=TLa*i25;                cB[4]=TLb*i25;                 // NW
    cA[5]=TRa*i25;                cB[5]=TRb*i25;                 // NE
    cA[6]=BLa*i25;                cB[6]=BLb*i25;                 // SW
    cA[7]=BRa*i25;                cB[7]=BRb*i25;                 // SE

    float best = 1e30f, bd = 0.f;
    #pragma unroll
    for (int i = 0; i < 8; ++i) {
        float d = cA[i] * xv + cB[i] - xv;
        float ad = fabsf(d);
        if (ad < best) { best = ad; bd = d; }   // strict < => first-occurrence
    }
    float res = truncf(bd + xv);
    res = fminf(fmaxf(res, 0.0f), 255.0f);
    out[(c * HRH + Y) * HRW + X] = res;
}

extern "C" void kernel_launch(void* const* d_in, const int* in_sizes, int n_in,
                              void* d_out, int out_size, void* d_ws, size_t ws_size,
                              hipStream_t stream) {
    const float* lrx = (const float*)d_in[0];
    const float* lry = (const float*)d_in[1];
    const float* hrx = (const float*)d_in[2];
    (void)d_in[3]; (void)in_sizes; (void)n_in; (void)out_size; (void)ws_size;

    float2* AB = (float2*)d_ws;                // 3*256*256 float2 = 1.5 MB
    float* outp = (float*)d_out;

    dim3 lgrid(LRW / TW, LRH / TH, 3);
    dim3 block(TW, TH);
    lowres_coeffs<<<lgrid, block, 0, stream>>>(lrx, lry, AB);

    dim3 grid(HRW / TW, HRH / TH, 3);
    stencil_kernel<<<grid, block, 0, stream>>>(AB, hrx, outp);
}

// Round 3
// 92.950 us; speedup vs baseline: 1.2630x; 1.0188x over previous
//
#include <hip/hip_runtime.h>

#define RR 4
#define LRH 256
#define LRW 256
#define HRH 1024
#define HRW 1024

// lowres tile
#define LTW 32
#define LTH 8
#define LGW (LTW + 2*RR)   // 40
#define LGH (LTH + 2*RR)   // 16

// stencil tile: 32x32 outputs per block, 4 rows per thread
#define STW 32
#define STH 32
#define RPT 4
#define SGW (STW + 2*RR)   // 40
#define SGH (STH + 2*RR)   // 40

// Kernel 1: low-res 9x9 box stats (replication pad = clamp) -> interleaved (A,B)
// Separable: stage (x,y,xy,xx) float4 -> horizontal 9-tap -> vertical 9-tap.
__global__ __launch_bounds__(256) void lowres_coeffs(
    const float* __restrict__ lrx, const float* __restrict__ lry,
    float2* __restrict__ AB)
{
    __shared__ float4 sV[LGH][LGW];   // x, y, xy, xx (padded tile)
    __shared__ float4 sH[LGH][LTW];   // horizontal 9-tap sums

    const int c  = blockIdx.z;
    const int X0 = blockIdx.x * LTW, Y0 = blockIdx.y * LTH;
    const int tid = threadIdx.y * LTW + threadIdx.x;
    const float* px = lrx + c * LRH * LRW;
    const float* py = lry + c * LRH * LRW;

    for (int i = tid; i < LGH * LGW; i += 256) {
        int r = i / LGW, col = i - r * LGW;
        int gy = min(max(Y0 - RR + r, 0), LRH - 1);
        int gx = min(max(X0 - RR + col, 0), LRW - 1);
        float xv = px[gy * LRW + gx];
        float yv = py[gy * LRW + gx];
        sV[r][col] = make_float4(xv, yv, xv * yv, xv * xv);
    }
    __syncthreads();

    for (int i = tid; i < LGH * LTW; i += 256) {
        int r = i / LTW, col = i - r * LTW;
        float4 s = sV[r][col];
        #pragma unroll
        for (int k = 1; k < 9; ++k) {
            float4 v = sV[r][col + k];
            s.x += v.x; s.y += v.y; s.z += v.z; s.w += v.w;
        }
        sH[r][col] = s;
    }
    __syncthreads();

    const int tx = threadIdx.x, ty = threadIdx.y;
    float4 s = sH[ty][tx];
    #pragma unroll
    for (int k = 1; k < 9; ++k) {
        float4 v = sH[ty + k][tx];
        s.x += v.x; s.y += v.y; s.z += v.z; s.w += v.w;
    }
    const float inv81 = 1.0f / 81.0f;
    float mx = s.x * inv81, my = s.y * inv81;
    float cov = s.z * inv81 - mx * my;
    float var = s.w * inv81 - mx * mx;
    float A = cov / (var + 2.0f);
    float B = my - A * mx;
    AB[(c * LRH + Y0 + ty) * LRW + X0 + tx] = make_float2(A, B);
}

// Kernel 2: fused bilinear upsample (align_corners=True) + 8-dir side-window
// stencil + argmin|d| + trunc/clamp. 32x32 tile, 4 rows/thread with a
// register sliding window over the vertical 9-tap.
__global__ __launch_bounds__(256) void stencil_kernel(
    const float2* __restrict__ AB,
    const float* __restrict__ hrx, float* __restrict__ out)
{
    __shared__ float2 sAB[SGH][SGW];  // upsampled (A,B), padded tile (12.8 KB)
    __shared__ float4 sH[SGH][STW];   // hLa,hLb,hRa,hRb per (row, inner col) (20.5 KB)

    const int c  = blockIdx.z;
    const int X0 = blockIdx.x * STW, Y0 = blockIdx.y * STH;
    const int tid = threadIdx.y * STW + threadIdx.x;
    const float2* ABc = AB + c * LRH * LRW;
    const float scale = 255.0f / 1023.0f;  // (src-1)/(out-1)

    // Stage upsampled A,B padded tile (hr coords clamped = rep-pad)
    for (int i = tid; i < SGH * SGW; i += 256) {
        int r = i / SGW, col = i - r * SGW;
        int gy = min(max(Y0 - RR + r, 0), HRH - 1);
        int gx = min(max(X0 - RR + col, 0), HRW - 1);
        float tyf = (float)gy * scale;
        int iy = (int)tyf; if (iy > LRH - 2) iy = LRH - 2;
        float fy = tyf - (float)iy;
        float txf = (float)gx * scale;
        int ix = (int)txf; if (ix > LRW - 2) ix = LRW - 2;
        float fx = txf - (float)ix;
        float2 v00 = ABc[iy * LRW + ix];
        float2 v01 = ABc[iy * LRW + ix + 1];
        float2 v10 = ABc[(iy + 1) * LRW + ix];
        float2 v11 = ABc[(iy + 1) * LRW + ix + 1];
        float a0 = v00.x * (1.0f - fy) + v10.x * fy;
        float a1 = v01.x * (1.0f - fy) + v11.x * fy;
        float b0 = v00.y * (1.0f - fy) + v10.y * fy;
        float b1 = v01.y * (1.0f - fy) + v11.y * fy;
        sAB[r][col] = make_float2(a0 * (1.0f - fx) + a1 * fx,
                                  b0 * (1.0f - fx) + b1 * fx);
    }
    __syncthreads();

    // Horizontal half-window sums: hL = cols [c..c+4], hR = cols [c+4..c+8]
    for (int i = tid; i < SGH * STW; i += 256) {
        int r = i / STW, col = i - r * STW;
        float hLa = 0, hLb = 0, hRa = 0, hRb = 0;
        #pragma unroll
        for (int k = 0; k <= 4; ++k) {
            float2 v = sAB[r][col + k];
            hLa += v.x; hLb += v.y;
        }
        #pragma unroll
        for (int k = 4; k <= 8; ++k) {
            float2 v = sAB[r][col + k];
            hRa += v.x; hRb += v.y;
        }
        sH[r][col] = make_float4(hLa, hLb, hRa, hRb);
    }
    __syncthreads();

    const int tx = threadIdx.x;
    const int base = threadIdx.y * RPT;   // sH row of j=0's window start

    // Load this column's 12 rows of (hL,hR) and 12 center values once.
    float4 h[RPT + 8];
    float2 cv[RPT + 8];
    #pragma unroll
    for (int k = 0; k < RPT + 8; ++k) {
        h[k]  = sH[base + k][tx];
        cv[k] = sAB[base + k][tx + RR];
    }

    // Init vertical sums for j=0: T = rows [0..4], B = rows [4..8]
    float4 T = h[0], B = h[4];
    float2 Tc = cv[0], Bc = cv[4];
    #pragma unroll
    for (int k = 1; k <= 4; ++k) {
        T.x += h[k].x; T.y += h[k].y; T.z += h[k].z; T.w += h[k].w;
        B.x += h[k+4].x; B.y += h[k+4].y; B.z += h[k+4].z; B.w += h[k+4].w;
        Tc.x += cv[k].x; Tc.y += cv[k].y;
        Bc.x += cv[k+4].x; Bc.y += cv[k+4].y;
    }

    const float i45 = 1.0f / 45.0f, i25 = 1.0f / 25.0f;
    const int X = X0 + tx;

    #pragma unroll
    for (int j = 0; j < RPT; ++j) {
        float4 C  = h[j + 4];
        float2 Cc = cv[j + 4];
        const int Y = Y0 + base + j;
        float xv = hrx[(c * HRH + Y) * HRW + X];

        float cA[8], cB[8];
        cA[0] = (T.x + B.x - C.x) * i45;  cB[0] = (T.y + B.y - C.y) * i45;   // L
        cA[1] = (T.z + B.z - C.z) * i45;  cB[1] = (T.w + B.w - C.w) * i45;   // R
        cA[2] = (T.x + T.z - Tc.x) * i45; cB[2] = (T.y + T.w - Tc.y) * i45;  // U
        cA[3] = (B.x + B.z - Bc.x) * i45; cB[3] = (B.y + B.w - Bc.y) * i45;  // D
        cA[4] = T.x * i25;                cB[4] = T.y * i25;                 // NW
        cA[5] = T.z * i25;                cB[5] = T.w * i25;                 // NE
        cA[6] = B.x * i25;                cB[6] = B.y * i25;                 // SW
        cA[7] = B.z * i25;                cB[7] = B.w * i25;                 // SE

        float best = 1e30f, bd = 0.f;
        #pragma unroll
        for (int i = 0; i < 8; ++i) {
            float d = cA[i] * xv + cB[i] - xv;
            float ad = fabsf(d);
            if (ad < best) { best = ad; bd = d; }   // strict < => first-occurrence
        }
        float res = truncf(bd + xv);
        res = fminf(fmaxf(res, 0.0f), 255.0f);
        out[(c * HRH + Y) * HRW + X] = res;

        // Slide window down one row
        if (j < RPT - 1) {
            T.x += h[j+5].x - h[j].x;   T.y += h[j+5].y - h[j].y;
            T.z += h[j+5].z - h[j].z;   T.w += h[j+5].w - h[j].w;
            B.x += h[j+9].x - h[j+4].x; B.y += h[j+9].y - h[j+4].y;
            B.z += h[j+9].z - h[j+4].z; B.w += h[j+9].w - h[j+4].w;
            Tc.x += cv[j+5].x - cv[j].x;   Tc.y += cv[j+5].y - cv[j].y;
            Bc.x += cv[j+9].x - cv[j+4].x; Bc.y += cv[j+9].y - cv[j+4].y;
        }
    }
}

extern "C" void kernel_launch(void* const* d_in, const int* in_sizes, int n_in,
                              void* d_out, int out_size, void* d_ws, size_t ws_size,
                              hipStream_t stream) {
    const float* lrx = (const float*)d_in[0];
    const float* lry = (const float*)d_in[1];
    const float* hrx = (const float*)d_in[2];
    (void)d_in[3]; (void)in_sizes; (void)n_in; (void)out_size; (void)ws_size;

    float2* AB = (float2*)d_ws;                // 3*256*256 float2 = 1.5 MB
    float* outp = (float*)d_out;

    dim3 lblock(LTW, LTH);
    dim3 lgrid(LRW / LTW, LRH / LTH, 3);
    lowres_coeffs<<<lgrid, lblock, 0, stream>>>(lrx, lry, AB);

    dim3 sblock(STW, STH / RPT);
    dim3 sgrid(HRW / STW, HRH / STH, 3);
    stencil_kernel<<<sgrid, sblock, 0, stream>>>(AB, hrx, outp);
}